// Round 6
// baseline (705.731 us; speedup 1.0000x reference)
//
#include <hip/hip_runtime.h>
#include <cstdint>

#define NND 5000
#define NE 160000
#define NF 128
#define NH 256
#define NT 10
#define MT 10
#define NC 8
#define NMAT (NND*MT)      // 50000 per template
#define CG_ITERS 5
#define SINK_IT 30

// ---------------- wave-level f32 sum (DPP, VALU pipe — no LDS) ----------------
#if __has_builtin(__builtin_amdgcn_update_dpp)
#define DPP_ADD(x, ctrl, rmask) \
    ((x) + __int_as_float(__builtin_amdgcn_update_dpp(0, __float_as_int(x), (ctrl), (rmask), 0xf, true)))
__device__ __forceinline__ float wave_sum63(float x) {
    x = DPP_ADD(x, 0x111, 0xf);   // row_shr:1
    x = DPP_ADD(x, 0x112, 0xf);   // row_shr:2
    x = DPP_ADD(x, 0x114, 0xf);   // row_shr:4
    x = DPP_ADD(x, 0x118, 0xf);   // row_shr:8
    x = DPP_ADD(x, 0x142, 0xa);   // row_bcast:15 -> rows 1,3
    x = DPP_ADD(x, 0x143, 0xc);   // row_bcast:31 -> rows 2,3
    return x;                      // lane 63 = full 64-lane sum
}
#else
__device__ __forceinline__ float wave_sum63(float x) {
#pragma unroll
    for (int off = 32; off; off >>= 1) x += __shfl_xor(x, off);
    return x;
}
#endif

__device__ __forceinline__ float frcp(float x) {
#if __has_builtin(__builtin_amdgcn_rcpf)
    return __builtin_amdgcn_rcpf(x);   // v_rcp_f32, ~1 ulp
#else
    return 1.f / x;
#endif
}

// ---------------- graph prep (merged) ----------------

__global__ void k_edge1(const int* __restrict__ src, const int* __restrict__ dst,
                        int* __restrict__ cntD, unsigned* __restrict__ bitmap,
                        int* __restrict__ cntS, unsigned char* __restrict__ keep) {
    for (int e = blockIdx.x*blockDim.x + threadIdx.x; e < NE; e += gridDim.x*blockDim.x) {
        int s = src[e], d = dst[e];
        atomicAdd(&cntD[d], 1);
        int key = s * NND + d;
        unsigned bit = 1u << (key & 31);
        unsigned old = atomicOr(&bitmap[key >> 5], bit);
        if (!(old & bit)) { keep[e] = 1; atomicAdd(&cntS[s], 1); }
        else keep[e] = 0;
    }
}

// block 0: cntD -> rpD (+ dinv); block 1: cntS -> rpS (+ c1row); block 2: c2row
__global__ void k_exscan2(const int* __restrict__ cntD, int* __restrict__ rpD,
                          float* __restrict__ dinv,
                          const int* __restrict__ cntS, int* __restrict__ rpS,
                          float* __restrict__ c1row,
                          const float* __restrict__ tpl, float* __restrict__ c2row) {
    const int T = 1024;
    int tid = threadIdx.x;
    if (blockIdx.x == 2) {
        if (tid < NT * MT) {
            int t = tid / MT, j = tid % MT;
            float s = 0.f;
            for (int k = 0; k < MT; k++) { float v = tpl[t * 100 + j * 10 + k]; s += v * v; }
            c2row[tid] = s * (1.f / MT);
        }
        return;
    }
    const int* cnt = blockIdx.x ? cntS : cntD;
    int* rp = blockIdx.x ? rpS : rpD;
    int C = (NND + T - 1) / T;
    int begin = tid * C, end = begin + C; if (end > NND) end = NND; if (begin > NND) begin = NND;
    int s = 0;
    for (int i = begin; i < end; i++) s += cnt[i];
    __shared__ int part[1024];
    part[tid] = s; __syncthreads();
    for (int off = 1; off < T; off <<= 1) {
        int v = (tid >= off) ? part[tid - off] : 0;
        __syncthreads();
        part[tid] += v;
        __syncthreads();
    }
    int run = part[tid] - s;   // exclusive
    for (int i = begin; i < end; i++) { rp[i] = run; run += cnt[i]; }
    if (tid == T - 1) rp[NND] = part[T - 1];
    if (blockIdx.x == 0)
        for (int i = begin; i < end; i++) dinv[i] = rsqrtf((float)(cnt[i] + 1));
    else
        for (int i = begin; i < end; i++) c1row[i] = (float)cnt[i] * (1.f / NND);
}

__global__ void k_scatter2(const int* __restrict__ src, const int* __restrict__ dst,
                           const unsigned char* __restrict__ keep,
                           const int* __restrict__ rpD, int* __restrict__ cur1,
                           int* __restrict__ csrS, float* __restrict__ csrC,
                           const float* __restrict__ dinv,
                           const int* __restrict__ rpS, int* __restrict__ cur2,
                           int* __restrict__ csrD) {
    for (int e = blockIdx.x*blockDim.x + threadIdx.x; e < NE; e += gridDim.x*blockDim.x) {
        int s = src[e], d = dst[e];
        int pos = rpD[d] + atomicAdd(&cur1[d], 1);
        csrS[pos] = s;
        csrC[pos] = dinv[s] * dinv[d];
        if (keep[e]) {
            int p2 = rpS[s] + atomicAdd(&cur2[s], 1);
            csrD[p2] = d;
        }
    }
}

// ---------------- GCN ----------------
// GCN layer = agg(x @ W) + b; aggregation is linear in features, so layer 1
// uses (agg x) @ W + b (aggregate 128-dim rows instead of 256-dim).

__global__ __launch_bounds__(256) void k_gemm(const float* __restrict__ A,
                                              const float* __restrict__ B,
                                              float* __restrict__ C, int M, int N, int K,
                                              const float* __restrict__ bias, int relu) {
    const int BM = 64, BN = 64, BK = 16;
    __shared__ float As[BK][BM + 1];
    __shared__ float Bs[BK][BN];
    int tid = threadIdx.x;
    int row0 = blockIdx.y * BM, col0 = blockIdx.x * BN;
    int tx = tid % 16, ty = tid / 16;
    float acc[4][4] = {};
    for (int k0 = 0; k0 < K; k0 += BK) {
#pragma unroll
        for (int l = 0; l < 4; l++) {
            int idx = tid + l * 256;
            int r = idx / BK, kk = idx % BK;
            int gr = row0 + r;
            As[kk][r] = (gr < M) ? A[(size_t)gr * K + k0 + kk] : 0.f;
        }
#pragma unroll
        for (int l = 0; l < 4; l++) {
            int idx = tid + l * 256;
            int kk = idx / BN, c = idx % BN;
            Bs[kk][c] = B[(size_t)(k0 + kk) * N + col0 + c];
        }
        __syncthreads();
#pragma unroll
        for (int kk = 0; kk < BK; kk++) {
            float a[4], b[4];
#pragma unroll
            for (int i = 0; i < 4; i++) a[i] = As[kk][ty * 4 + i];
#pragma unroll
            for (int j = 0; j < 4; j++) b[j] = Bs[kk][tx * 4 + j];
#pragma unroll
            for (int i = 0; i < 4; i++)
#pragma unroll
                for (int j = 0; j < 4; j++) acc[i][j] += a[i] * b[j];
        }
        __syncthreads();
    }
#pragma unroll
    for (int i = 0; i < 4; i++) {
        int gr = row0 + ty * 4 + i;
        if (gr < M) {
#pragma unroll
            for (int j = 0; j < 4; j++) {
                int gc = col0 + tx * 4 + j;
                float o = acc[i][j];
                if (bias) o += bias[gc];
                if (relu) o = fmaxf(o, 0.f);
                C[(size_t)gr * N + gc] = o;
            }
        }
    }
}

// aggregation over 128-dim rows: 8 nodes per 256-block, 32 lanes x float4 per node
__global__ __launch_bounds__(256) void k_aggregate(const float4* __restrict__ hin4,
                            const float* __restrict__ bias,
                            float4* __restrict__ hout4, const int* __restrict__ rp,
                            const int* __restrict__ csrS, const float* __restrict__ csrC,
                            const float* __restrict__ dinv) {
    int v = blockIdx.x * 8 + (threadIdx.x >> 5);
    int l = threadIdx.x & 31;
    float dv = dinv[v];
    float sc = dv * dv;
    float4 a = hin4[(size_t)v * 32 + l];
    float4 acc = make_float4(a.x * sc, a.y * sc, a.z * sc, a.w * sc);
    int e0 = rp[v], e1 = rp[v + 1];
    for (int e = e0; e < e1; e++) {
        int s = csrS[e];
        float c = csrC[e];
        float4 hv = hin4[(size_t)s * 32 + l];
        acc.x = fmaf(hv.x, c, acc.x);
        acc.y = fmaf(hv.y, c, acc.y);
        acc.z = fmaf(hv.z, c, acc.z);
        acc.w = fmaf(hv.w, c, acc.w);
    }
    if (bias) {
        float4 bb = ((const float4*)bias)[l];
        acc.x += bb.x; acc.y += bb.y; acc.z += bb.z; acc.w += bb.w;
    }
    hout4[(size_t)v * 32 + l] = acc;
}

// ---------------- FGW prep ----------------

// feature cost M (sx, sF inline; float4 inner loops)
__global__ __launch_bounds__(128) void k_M(const float* __restrict__ h,
                    const float* __restrict__ tplF,
                    float* __restrict__ Mout) {
    int i = blockIdx.x;
    int tid = threadIdx.x;
    int lane = tid & 63, w = tid >> 6;
    __shared__ float hrow[NF];
    __shared__ float part[2];
    float hv = h[(size_t)i * NF + tid];
    hrow[tid] = hv;
    float ps = wave_sum63(hv * hv);
    if (lane == 63) part[w] = ps;
    __syncthreads();
    float sx = part[0] + part[1];
    int c = tid;
    if (c < NT * MT) {
        const float4* Fc = (const float4*)(tplF + (size_t)c * NF);
        const float4* hr = (const float4*)hrow;
        float dot = 0.f, nrm = 0.f;
#pragma unroll 8
        for (int f = 0; f < NF / 4; f++) {
            float4 fv = Fc[f];
            float4 hq = hr[f];
            dot = fmaf(hq.x, fv.x, dot); dot = fmaf(hq.y, fv.y, dot);
            dot = fmaf(hq.z, fv.z, dot); dot = fmaf(hq.w, fv.w, dot);
            nrm = fmaf(fv.x, fv.x, nrm); nrm = fmaf(fv.y, fv.y, nrm);
            nrm = fmaf(fv.z, fv.z, nrm); nrm = fmaf(fv.w, fv.w, nrm);
        }
        int t = c / MT, j = c % MT;
        Mout[(size_t)t * NMAT + (size_t)i * MT + j] = sx + nrm - 2.f * dot;
    }
}

__global__ void k_Tinit(float* __restrict__ T) {
    for (int idx = blockIdx.x*blockDim.x + threadIdx.x; idx < NT * NMAT; idx += gridDim.x*blockDim.x)
        T[idx] = 1.f / (float)NMAT;
}

// ---------------- CG iteration ----------------

__global__ __launch_bounds__(256) void k_grad(const float* __restrict__ T, const float* __restrict__ Mm,
                                              const float* __restrict__ c1row, const float* __restrict__ c2row,
                                              const float* __restrict__ tpl,
                                              const int* __restrict__ rpS, const int* __restrict__ csrD,
                                              float* __restrict__ G, unsigned* __restrict__ scaleBits) {
    int t = blockIdx.y;
    int tid = threadIdx.x;
    __shared__ float tC2[100];
    if (tid < 100) tC2[tid] = 2.f * tpl[t * 100 + tid];
    __syncthreads();
    int i = blockIdx.x * 256 + tid;
    float amax = 0.f;
    if (i < NND) {
        const float* Tt = T + (size_t)t * NMAT;
        const float* Mt = Mm + (size_t)t * NMAT;
        float* Gt = G + (size_t)t * NMAT;
        float L[MT];
#pragma unroll
        for (int j = 0; j < MT; j++) L[j] = 0.f;
        int e0 = rpS[i], e1 = rpS[i + 1];
        for (int e = e0; e < e1; e++) {
            int k = csrD[e];
            const float* Tk = Tt + (size_t)k * MT;
#pragma unroll
            for (int j = 0; j < MT; j++) L[j] += Tk[j];
        }
        float c1 = c1row[i];
#pragma unroll
        for (int j = 0; j < MT; j++) {
            float s = 0.f;
#pragma unroll
            for (int k = 0; k < MT; k++) s += L[k] * tC2[j * 10 + k];
            float g = 0.5f * Mt[(size_t)i * MT + j] + (c1 + c2row[t * 10 + j] - s);
            Gt[(size_t)i * MT + j] = g;
            amax = fmaxf(amax, fabsf(g));
        }
    }
    __shared__ float red[256];
    red[tid] = amax; __syncthreads();
    for (int off = 128; off > 0; off >>= 1) {
        if (tid < off) red[tid] = fmaxf(red[tid], red[tid + off]);
        __syncthreads();
    }
    if (tid == 0) atomicMax(&scaleBits[t], __float_as_uint(red[0]));
}

// ---------------- sinkhorn: 1024 threads, 5 rows/thread, K in NAMED SCALARS ----
// Round-5 postmortem: Kf[10][10] (100 floats) was never promoted to VGPRs
// (VGPR_Count=72) -> scratch traffic dominated. Named scalars are pure SSA,
// trivially register-allocated; 1024-thread block caps at 128 VGPR (4 waves/EU),
// and ~100 live scalars fit.

#define SK_ROWS(X) X(0) X(1) X(2) X(3) X(4)

#define SK_DECL(r) float K##r##f0,K##r##f1,K##r##f2,K##r##f3,K##r##f4, \
                         K##r##f5,K##r##f6,K##r##f7,K##r##f8,K##r##f9, u##r;

#define SK_INIT(r) { int i = tid + (r)*1024; \
    if (i < NND) { \
        const float2* Gr = (const float2*)(Gt + (size_t)i*10); \
        float2 a=Gr[0], b=Gr[1], c=Gr[2], d=Gr[3], e=Gr[4]; \
        K##r##f0=__expf(a.x*inv); K##r##f1=__expf(a.y*inv); \
        K##r##f2=__expf(b.x*inv); K##r##f3=__expf(b.y*inv); \
        K##r##f4=__expf(c.x*inv); K##r##f5=__expf(c.y*inv); \
        K##r##f6=__expf(d.x*inv); K##r##f7=__expf(d.y*inv); \
        K##r##f8=__expf(e.x*inv); K##r##f9=__expf(e.y*inv); \
        u##r = 1.f; \
    } else { \
        K##r##f0=K##r##f1=K##r##f2=K##r##f3=K##r##f4=0.f; \
        K##r##f5=K##r##f6=K##r##f7=K##r##f8=K##r##f9=0.f; \
        u##r = 0.f; } }

#define SK_COL(r) { float ur = u##r; \
    S0=fmaf(K##r##f0,ur,S0); S1=fmaf(K##r##f1,ur,S1); \
    S2=fmaf(K##r##f2,ur,S2); S3=fmaf(K##r##f3,ur,S3); \
    S4=fmaf(K##r##f4,ur,S4); S5=fmaf(K##r##f5,ur,S5); \
    S6=fmaf(K##r##f6,ur,S6); S7=fmaf(K##r##f7,ur,S7); \
    S8=fmaf(K##r##f8,ur,S8); S9=fmaf(K##r##f9,ur,S9); }

#define SK_RED(j) { float s = wave_sum63(S##j); if (lane == 63) wred[w][j] = s; }

#define SK_ROW(r) { float R = 0.f; \
    R=fmaf(K##r##f0,V0,R); R=fmaf(K##r##f1,V1,R); \
    R=fmaf(K##r##f2,V2,R); R=fmaf(K##r##f3,V3,R); \
    R=fmaf(K##r##f4,V4,R); R=fmaf(K##r##f5,V5,R); \
    R=fmaf(K##r##f6,V6,R); R=fmaf(K##r##f7,V7,R); \
    R=fmaf(K##r##f8,V8,R); R=fmaf(K##r##f9,V9,R); \
    u##r = 2e-4f * frcp(fmaxf(R, 1e-30f)); }

#define SK_TUPD(r) { int i = tid + (r)*1024; \
    if (i < NND) { float ur = u##r; \
        float2* Tr = (float2*)(Tt + (size_t)i*10); float2 v; \
        v=Tr[0]; v.x+=step*(ur*K##r##f0*V0-v.x); v.y+=step*(ur*K##r##f1*V1-v.y); Tr[0]=v; \
        v=Tr[1]; v.x+=step*(ur*K##r##f2*V2-v.x); v.y+=step*(ur*K##r##f3*V3-v.y); Tr[1]=v; \
        v=Tr[2]; v.x+=step*(ur*K##r##f4*V4-v.x); v.y+=step*(ur*K##r##f5*V5-v.y); Tr[2]=v; \
        v=Tr[3]; v.x+=step*(ur*K##r##f6*V6-v.x); v.y+=step*(ur*K##r##f7*V7-v.y); Tr[3]=v; \
        v=Tr[4]; v.x+=step*(ur*K##r##f8*V8-v.x); v.y+=step*(ur*K##r##f9*V9-v.y); Tr[4]=v; } }

__global__ __launch_bounds__(1024)
void k_sinkhorn(const float* __restrict__ G,
                const unsigned* __restrict__ scaleBits,
                float* __restrict__ T, float step) {
    int t = blockIdx.x;
    int tid = threadIdx.x;
    int lane = tid & 63, w = tid >> 6;
    float sc = __uint_as_float(scaleBits[t]) + 1e-9f;
    float inv = -1.f / (0.02f * sc);
    const float* Gt = G + (size_t)t * NMAT;
    float* Tt = T + (size_t)t * NMAT;

    __shared__ float wred[16][10];
    __shared__ float vbc[12];

    SK_ROWS(SK_DECL)
    SK_ROWS(SK_INIT)

    float V0,V1,V2,V3,V4,V5,V6,V7,V8,V9;
    V0=V1=V2=V3=V4=V5=V6=V7=V8=V9=0.f;

    for (int it = 0; it < SINK_IT; it++) {
        float S0,S1,S2,S3,S4,S5,S6,S7,S8,S9;
        S0=S1=S2=S3=S4=S5=S6=S7=S8=S9=0.f;
        SK_ROWS(SK_COL)
        SK_RED(0) SK_RED(1) SK_RED(2) SK_RED(3) SK_RED(4)
        SK_RED(5) SK_RED(6) SK_RED(7) SK_RED(8) SK_RED(9)
        __syncthreads();
        if (tid < 10) {
            float s = 0.f;
#pragma unroll
            for (int q = 0; q < 16; q++) s += wred[q][tid];
            vbc[tid] = 0.1f * frcp(fmaxf(s, 1e-30f));   // v = q / (K^T u)
        }
        __syncthreads();
        V0=vbc[0]; V1=vbc[1]; V2=vbc[2]; V3=vbc[3]; V4=vbc[4];
        V5=vbc[5]; V6=vbc[6]; V7=vbc[7]; V8=vbc[8]; V9=vbc[9];
        SK_ROWS(SK_ROW)      // u = p / (K v)
    }

    SK_ROWS(SK_TUPD)         // T += step * (u K v - T)
}

// ---------------- final distance + head ----------------

__global__ __launch_bounds__(256) void k_final(const float* __restrict__ T, const float* __restrict__ Mm,
                                               const float* __restrict__ c1row, const float* __restrict__ c2row,
                                               const float* __restrict__ tpl,
                                               const int* __restrict__ rpS, const int* __restrict__ csrD,
                                               double* __restrict__ dd) {
    int t = blockIdx.y;
    int tid = threadIdx.x;
    __shared__ float tC2[100];
    if (tid < 100) tC2[tid] = 2.f * tpl[t * 100 + tid];
    __syncthreads();
    int i = blockIdx.x * 256 + tid;
    double msum = 0.0, tsum = 0.0;
    if (i < NND) {
        const float* Tt = T + (size_t)t * NMAT;
        const float* Mt = Mm + (size_t)t * NMAT;
        float L[MT];
#pragma unroll
        for (int j = 0; j < MT; j++) L[j] = 0.f;
        int e0 = rpS[i], e1 = rpS[i + 1];
        for (int e = e0; e < e1; e++) {
            int k = csrD[e];
            const float* Tk = Tt + (size_t)k * MT;
#pragma unroll
            for (int j = 0; j < MT; j++) L[j] += Tk[j];
        }
        float c1 = c1row[i];
#pragma unroll
        for (int j = 0; j < MT; j++) {
            float s = 0.f;
#pragma unroll
            for (int k = 0; k < MT; k++) s += L[k] * tC2[j * 10 + k];
            float ts = c1 + c2row[t * 10 + j] - s;
            float Tv = Tt[(size_t)i * MT + j];
            msum += (double)(Mt[(size_t)i * MT + j] * Tv);
            tsum += (double)(ts * Tv);
        }
    }
    __shared__ double r1[256], r2[256];
    r1[tid] = msum; r2[tid] = tsum; __syncthreads();
    for (int off = 128; off > 0; off >>= 1) {
        if (tid < off) { r1[tid] += r1[tid + off]; r2[tid] += r2[tid + off]; }
        __syncthreads();
    }
    if (tid == 0) { atomicAdd(&dd[t * 2], r1[0]); atomicAdd(&dd[t * 2 + 1], r2[0]); }
}

__global__ void k_out(const double* __restrict__ dd, const float* __restrict__ Wlin,
                      const float* __restrict__ blin, float* __restrict__ out) {
    int tid = threadIdx.x;
    __shared__ float ds[NT];
    if (tid < NT) ds[tid] = 0.5f * (float)(dd[2 * tid] + dd[2 * tid + 1]);
    __syncthreads();
    if (tid < NC) {
        float o = blin[tid];
#pragma unroll
        for (int t = 0; t < NT; t++) o += ds[t] * Wlin[t * NC + tid];
        out[tid] = o;
    }
}

// ---------------- host ----------------

extern "C" void kernel_launch(void* const* d_in, const int* in_sizes, int n_in,
                              void* d_out, int out_size, void* d_ws, size_t ws_size,
                              hipStream_t stream) {
    const float* x    = (const float*)d_in[0];
    const int*   ei   = (const int*)d_in[1];
    const int*   src  = ei;
    const int*   dst  = ei + NE;
    const float* W1   = (const float*)d_in[2];
    const float* b1   = (const float*)d_in[3];
    const float* W2   = (const float*)d_in[4];
    const float* b2   = (const float*)d_in[5];
    const float* tpl  = (const float*)d_in[6];
    const float* tplF = (const float*)d_in[7];
    const float* Wlin = (const float*)d_in[8];
    const float* blin = (const float*)d_in[9];
    float* out = (float*)d_out;

    char* w = (char*)d_ws;
    size_t off = 0;
    auto alloc = [&](size_t b) -> char* {
        off = (off + 255) & ~(size_t)255;
        char* p = w + off; off += b; return p;
    };
    float* bufA = (float*)alloc((size_t)NND * NH * 4);   // aggX / t2 (reused)
    float* bufB = (float*)alloc((size_t)NND * NH * 4);   // h1
    float* bufH = (float*)alloc((size_t)NND * NF * 4);   // h2
    float* Mm   = (float*)alloc((size_t)NT * NMAT * 4);
    float* T    = (float*)alloc((size_t)NT * NMAT * 4);
    float* G    = (float*)alloc((size_t)NT * NMAT * 4);
    // --- zero group (one memset) ---
    int* cntD = (int*)alloc((size_t)NND * 4);
    int* cntS = (int*)alloc((size_t)NND * 4);
    int* cur1 = (int*)alloc((size_t)NND * 4);
    int* cur2 = (int*)alloc((size_t)NND * 4);
    double* dd = (double*)alloc((size_t)NT * 2 * 8);
    unsigned* scaleArr = (unsigned*)alloc((size_t)CG_ITERS * NT * 4);
    char* zend = w + off;
    // --- rest ---
    unsigned* bitmap = (unsigned*)alloc((size_t)781250 * 4);
    int* rpD  = (int*)alloc((size_t)(NND + 1) * 4);
    int* rpS  = (int*)alloc((size_t)(NND + 1) * 4);
    int* csrS = (int*)alloc((size_t)NE * 4);
    float* csrC = (float*)alloc((size_t)NE * 4);
    int* csrD2 = (int*)alloc((size_t)NE * 4);
    unsigned char* keep = (unsigned char*)alloc((size_t)NE);
    float* dinv  = (float*)alloc((size_t)NND * 4);
    float* c1row = (float*)alloc((size_t)NND * 4);
    float* c2row = (float*)alloc((size_t)100 * 4);

    hipMemsetAsync(cntD, 0, (size_t)(zend - (char*)cntD), stream);
    hipMemsetAsync(bitmap, 0, (size_t)781250 * 4, stream);

    // graph prep (merged passes)
    k_edge1<<<625, 256, 0, stream>>>(src, dst, cntD, bitmap, cntS, keep);
    k_exscan2<<<3, 1024, 0, stream>>>(cntD, rpD, dinv, cntS, rpS, c1row, tpl, c2row);
    k_scatter2<<<625, 256, 0, stream>>>(src, dst, keep, rpD, cur1, csrS, csrC, dinv,
                                        rpS, cur2, csrD2);

    // GCN: layer1 = relu((agg x) @ W1 + b1); layer2 = agg(h1 @ W2) + b2
    k_aggregate<<<625, 256, 0, stream>>>((const float4*)x, nullptr, (float4*)bufA,
                                         rpD, csrS, csrC, dinv);
    k_gemm<<<dim3(NH / 64, (NND + 63) / 64), 256, 0, stream>>>(bufA, W1, bufB, NND, NH, NF, b1, 1);
    k_gemm<<<dim3(NF / 64, (NND + 63) / 64), 256, 0, stream>>>(bufB, W2, bufA, NND, NF, NH, nullptr, 0);
    k_aggregate<<<625, 256, 0, stream>>>((const float4*)bufA, b2, (float4*)bufH,
                                         rpD, csrS, csrC, dinv);

    // FGW prep
    k_M<<<NND, 128, 0, stream>>>(bufH, tplF, Mm);
    k_Tinit<<<1954, 256, 0, stream>>>(T);

    // conditional gradient loop (scale slots pre-zeroed, one per CG iter)
    for (int t = 0; t < CG_ITERS; t++) {
        unsigned* sb = scaleArr + t * NT;
        k_grad<<<dim3(20, NT), 256, 0, stream>>>(T, Mm, c1row, c2row, tpl, rpS, csrD2, G, sb);
        float step = 2.f / (float)(t + 2);
        k_sinkhorn<<<NT, 1024, 0, stream>>>(G, sb, T, step);
    }

    // final distances + linear head
    k_final<<<dim3(20, NT), 256, 0, stream>>>(T, Mm, c1row, c2row, tpl, rpS, csrD2, dd);
    k_out<<<1, 64, 0, stream>>>(dd, Wlin, blin, out);
}

// Round 7
// 687.703 us; speedup vs baseline: 1.0262x; 1.0262x over previous
//
#include <hip/hip_runtime.h>
#include <cstdint>

#define NND 5000
#define NE 160000
#define NF 128
#define NH 256
#define NT 10
#define MT 10
#define NC 8
#define NMAT (NND*MT)      // 50000 per template
#define CG_ITERS 5
#define SINK_IT 30

// ---------------- wave-level f32 sum (DPP, VALU pipe — no LDS) ----------------
#if __has_builtin(__builtin_amdgcn_update_dpp)
#define DPP_ADD(x, ctrl, rmask) \
    ((x) + __int_as_float(__builtin_amdgcn_update_dpp(0, __float_as_int(x), (ctrl), (rmask), 0xf, true)))
__device__ __forceinline__ float wave_sum63(float x) {
    x = DPP_ADD(x, 0x111, 0xf);   // row_shr:1
    x = DPP_ADD(x, 0x112, 0xf);   // row_shr:2
    x = DPP_ADD(x, 0x114, 0xf);   // row_shr:4
    x = DPP_ADD(x, 0x118, 0xf);   // row_shr:8
    x = DPP_ADD(x, 0x142, 0xa);   // row_bcast:15 -> rows 1,3
    x = DPP_ADD(x, 0x143, 0xc);   // row_bcast:31 -> rows 2,3
    return x;                      // lane 63 = full 64-lane sum
}
#else
__device__ __forceinline__ float wave_sum63(float x) {
#pragma unroll
    for (int off = 32; off; off >>= 1) x += __shfl_xor(x, off);
    return x;
}
#endif

__device__ __forceinline__ float frcp(float x) {
#if __has_builtin(__builtin_amdgcn_rcpf)
    return __builtin_amdgcn_rcpf(x);   // v_rcp_f32, ~1 ulp
#else
    return 1.f / x;
#endif
}

// ---------------- graph prep (merged) ----------------

__global__ void k_edge1(const int* __restrict__ src, const int* __restrict__ dst,
                        int* __restrict__ cntD, unsigned* __restrict__ bitmap,
                        int* __restrict__ cntS, unsigned char* __restrict__ keep) {
    for (int e = blockIdx.x*blockDim.x + threadIdx.x; e < NE; e += gridDim.x*blockDim.x) {
        int s = src[e], d = dst[e];
        atomicAdd(&cntD[d], 1);
        int key = s * NND + d;
        unsigned bit = 1u << (key & 31);
        unsigned old = atomicOr(&bitmap[key >> 5], bit);
        if (!(old & bit)) { keep[e] = 1; atomicAdd(&cntS[s], 1); }
        else keep[e] = 0;
    }
}

// block 0: cntD -> rpD (+ dinv); block 1: cntS -> rpS (+ c1row); block 2: c2row
__global__ void k_exscan2(const int* __restrict__ cntD, int* __restrict__ rpD,
                          float* __restrict__ dinv,
                          const int* __restrict__ cntS, int* __restrict__ rpS,
                          float* __restrict__ c1row,
                          const float* __restrict__ tpl, float* __restrict__ c2row) {
    const int T = 1024;
    int tid = threadIdx.x;
    if (blockIdx.x == 2) {
        if (tid < NT * MT) {
            int t = tid / MT, j = tid % MT;
            float s = 0.f;
            for (int k = 0; k < MT; k++) { float v = tpl[t * 100 + j * 10 + k]; s += v * v; }
            c2row[tid] = s * (1.f / MT);
        }
        return;
    }
    const int* cnt = blockIdx.x ? cntS : cntD;
    int* rp = blockIdx.x ? rpS : rpD;
    int C = (NND + T - 1) / T;
    int begin = tid * C, end = begin + C; if (end > NND) end = NND; if (begin > NND) begin = NND;
    int s = 0;
    for (int i = begin; i < end; i++) s += cnt[i];
    __shared__ int part[1024];
    part[tid] = s; __syncthreads();
    for (int off = 1; off < T; off <<= 1) {
        int v = (tid >= off) ? part[tid - off] : 0;
        __syncthreads();
        part[tid] += v;
        __syncthreads();
    }
    int run = part[tid] - s;   // exclusive
    for (int i = begin; i < end; i++) { rp[i] = run; run += cnt[i]; }
    if (tid == T - 1) rp[NND] = part[T - 1];
    if (blockIdx.x == 0)
        for (int i = begin; i < end; i++) dinv[i] = rsqrtf((float)(cnt[i] + 1));
    else
        for (int i = begin; i < end; i++) c1row[i] = (float)cnt[i] * (1.f / NND);
}

__global__ void k_scatter2(const int* __restrict__ src, const int* __restrict__ dst,
                           const unsigned char* __restrict__ keep,
                           const int* __restrict__ rpD, int* __restrict__ cur1,
                           int* __restrict__ csrS, float* __restrict__ csrC,
                           const float* __restrict__ dinv,
                           const int* __restrict__ rpS, int* __restrict__ cur2,
                           int* __restrict__ csrD) {
    for (int e = blockIdx.x*blockDim.x + threadIdx.x; e < NE; e += gridDim.x*blockDim.x) {
        int s = src[e], d = dst[e];
        int pos = rpD[d] + atomicAdd(&cur1[d], 1);
        csrS[pos] = s;
        csrC[pos] = dinv[s] * dinv[d];
        if (keep[e]) {
            int p2 = rpS[s] + atomicAdd(&cur2[s], 1);
            csrD[p2] = d;
        }
    }
}

// ---------------- GCN ----------------
// GCN layer = agg(x @ W) + b; aggregation is linear in features, so layer 1
// uses (agg x) @ W + b (aggregate 128-dim rows instead of 256-dim).

__global__ __launch_bounds__(256) void k_gemm(const float* __restrict__ A,
                                              const float* __restrict__ B,
                                              float* __restrict__ C, int M, int N, int K,
                                              const float* __restrict__ bias, int relu) {
    const int BM = 64, BN = 64, BK = 16;
    __shared__ float As[BK][BM + 1];
    __shared__ float Bs[BK][BN];
    int tid = threadIdx.x;
    int row0 = blockIdx.y * BM, col0 = blockIdx.x * BN;
    int tx = tid % 16, ty = tid / 16;
    float acc[4][4] = {};
    for (int k0 = 0; k0 < K; k0 += BK) {
#pragma unroll
        for (int l = 0; l < 4; l++) {
            int idx = tid + l * 256;
            int r = idx / BK, kk = idx % BK;
            int gr = row0 + r;
            As[kk][r] = (gr < M) ? A[(size_t)gr * K + k0 + kk] : 0.f;
        }
#pragma unroll
        for (int l = 0; l < 4; l++) {
            int idx = tid + l * 256;
            int kk = idx / BN, c = idx % BN;
            Bs[kk][c] = B[(size_t)(k0 + kk) * N + col0 + c];
        }
        __syncthreads();
#pragma unroll
        for (int kk = 0; kk < BK; kk++) {
            float a[4], b[4];
#pragma unroll
            for (int i = 0; i < 4; i++) a[i] = As[kk][ty * 4 + i];
#pragma unroll
            for (int j = 0; j < 4; j++) b[j] = Bs[kk][tx * 4 + j];
#pragma unroll
            for (int i = 0; i < 4; i++)
#pragma unroll
                for (int j = 0; j < 4; j++) acc[i][j] += a[i] * b[j];
        }
        __syncthreads();
    }
#pragma unroll
    for (int i = 0; i < 4; i++) {
        int gr = row0 + ty * 4 + i;
        if (gr < M) {
#pragma unroll
            for (int j = 0; j < 4; j++) {
                int gc = col0 + tx * 4 + j;
                float o = acc[i][j];
                if (bias) o += bias[gc];
                if (relu) o = fmaxf(o, 0.f);
                C[(size_t)gr * N + gc] = o;
            }
        }
    }
}

// aggregation over 128-dim rows: 8 nodes per 256-block, 32 lanes x float4 per node
__global__ __launch_bounds__(256) void k_aggregate(const float4* __restrict__ hin4,
                            const float* __restrict__ bias,
                            float4* __restrict__ hout4, const int* __restrict__ rp,
                            const int* __restrict__ csrS, const float* __restrict__ csrC,
                            const float* __restrict__ dinv) {
    int v = blockIdx.x * 8 + (threadIdx.x >> 5);
    int l = threadIdx.x & 31;
    float dv = dinv[v];
    float sc = dv * dv;
    float4 a = hin4[(size_t)v * 32 + l];
    float4 acc = make_float4(a.x * sc, a.y * sc, a.z * sc, a.w * sc);
    int e0 = rp[v], e1 = rp[v + 1];
    for (int e = e0; e < e1; e++) {
        int s = csrS[e];
        float c = csrC[e];
        float4 hv = hin4[(size_t)s * 32 + l];
        acc.x = fmaf(hv.x, c, acc.x);
        acc.y = fmaf(hv.y, c, acc.y);
        acc.z = fmaf(hv.z, c, acc.z);
        acc.w = fmaf(hv.w, c, acc.w);
    }
    if (bias) {
        float4 bb = ((const float4*)bias)[l];
        acc.x += bb.x; acc.y += bb.y; acc.z += bb.z; acc.w += bb.w;
    }
    hout4[(size_t)v * 32 + l] = acc;
}

// ---------------- FGW prep ----------------

// feature cost M (sx, sF inline) + T init folded in (kills k_Tinit dispatch)
__global__ __launch_bounds__(128) void k_M(const float* __restrict__ h,
                    const float* __restrict__ tplF,
                    float* __restrict__ Mout, float* __restrict__ T) {
    int i = blockIdx.x;
    int tid = threadIdx.x;
    int lane = tid & 63, w = tid >> 6;
    __shared__ float hrow[NF];
    __shared__ float part[2];
    float hv = h[(size_t)i * NF + tid];
    hrow[tid] = hv;
    float ps = wave_sum63(hv * hv);
    if (lane == 63) part[w] = ps;
    __syncthreads();
    float sx = part[0] + part[1];
    int c = tid;
    if (c < NT * MT) {
        const float4* Fc = (const float4*)(tplF + (size_t)c * NF);
        const float4* hr = (const float4*)hrow;
        float dot = 0.f, nrm = 0.f;
#pragma unroll 8
        for (int f = 0; f < NF / 4; f++) {
            float4 fv = Fc[f];
            float4 hq = hr[f];
            dot = fmaf(hq.x, fv.x, dot); dot = fmaf(hq.y, fv.y, dot);
            dot = fmaf(hq.z, fv.z, dot); dot = fmaf(hq.w, fv.w, dot);
            nrm = fmaf(fv.x, fv.x, nrm); nrm = fmaf(fv.y, fv.y, nrm);
            nrm = fmaf(fv.z, fv.z, nrm); nrm = fmaf(fv.w, fv.w, nrm);
        }
        int t = c / MT, j = c % MT;
        Mout[(size_t)t * NMAT + (size_t)i * MT + j] = sx + nrm - 2.f * dot;
        T[(size_t)t * NMAT + (size_t)i * MT + j] = 1.f / (float)NMAT;
    }
}

// ---------------- CG iteration ----------------

__global__ __launch_bounds__(256) void k_grad(const float* __restrict__ T, const float* __restrict__ Mm,
                                              const float* __restrict__ c1row, const float* __restrict__ c2row,
                                              const float* __restrict__ tpl,
                                              const int* __restrict__ rpS, const int* __restrict__ csrD,
                                              float* __restrict__ G, unsigned* __restrict__ scaleBits) {
    int t = blockIdx.y;
    int tid = threadIdx.x;
    __shared__ float tC2[100];
    if (tid < 100) tC2[tid] = 2.f * tpl[t * 100 + tid];
    __syncthreads();
    int i = blockIdx.x * 256 + tid;
    float amax = 0.f;
    if (i < NND) {
        const float* Tt = T + (size_t)t * NMAT;
        const float* Mt = Mm + (size_t)t * NMAT;
        float* Gt = G + (size_t)t * NMAT;
        float L[MT];
#pragma unroll
        for (int j = 0; j < MT; j++) L[j] = 0.f;
        int e0 = rpS[i], e1 = rpS[i + 1];
        for (int e = e0; e < e1; e++) {
            int k = csrD[e];
            const float* Tk = Tt + (size_t)k * MT;
#pragma unroll
            for (int j = 0; j < MT; j++) L[j] += Tk[j];
        }
        float c1 = c1row[i];
#pragma unroll
        for (int j = 0; j < MT; j++) {
            float s = 0.f;
#pragma unroll
            for (int k = 0; k < MT; k++) s += L[k] * tC2[j * 10 + k];
            float g = 0.5f * Mt[(size_t)i * MT + j] + (c1 + c2row[t * 10 + j] - s);
            Gt[(size_t)i * MT + j] = g;
            amax = fmaxf(amax, fabsf(g));
        }
    }
    __shared__ float red[256];
    red[tid] = amax; __syncthreads();
    for (int off = 128; off > 0; off >>= 1) {
        if (tid < off) red[tid] = fmaxf(red[tid], red[tid + off]);
        __syncthreads();
    }
    if (tid == 0) atomicMax(&scaleBits[t], __float_as_uint(red[0]));
}

// ---------------- sinkhorn ----------------
// One block per template, 512 threads, 10 rows/thread, all-f32 scaling form.
// Register forcing: flat_work_group_size(512,512) + waves_per_eu(2,2), and NO
// __launch_bounds__ (it also sets amdgpu-waves-per-eu and clobbered the
// attribute in round 5). 2 waves/EU => 256-reg total budget, so Kf[10][10]
// (~135 live floats) fits in ARCH VGPRs — rounds 4-6 allocated 52-72 arch regs
// and shuttled K through AGPR spills (v_accvgpr movs ~doubled VALU work).
__global__ __attribute__((amdgpu_flat_work_group_size(512, 512), amdgpu_waves_per_eu(2, 2)))
void k_sinkhorn(const float* __restrict__ G,
                const unsigned* __restrict__ scaleBits,
                float* __restrict__ T, float step) {
    int t = blockIdx.x;
    int tid = threadIdx.x;
    int lane = tid & 63, w = tid >> 6;
    float sc = __uint_as_float(scaleBits[t]) + 1e-9f;
    float inv = -1.f / (0.02f * sc);
    const float* Gt = G + (size_t)t * NMAT;
    float* Tt = T + (size_t)t * NMAT;

    __shared__ float wred[8][10];
    __shared__ float4 vbc4[3];     // 12 floats, 16B-aligned for b128 broadcast reads

    float Kf[10][10];
    float u[10];
#pragma unroll
    for (int r = 0; r < 10; r++) {
        int i = tid + r * 512;
        if (i < NND) {
            u[r] = 1.f;
            const float2* Gr = (const float2*)(Gt + (size_t)i * 10);
#pragma unroll
            for (int h = 0; h < 5; h++) {
                float2 g = Gr[h];
                Kf[r][2*h]   = __expf(g.x * inv);
                Kf[r][2*h+1] = __expf(g.y * inv);
            }
        } else {
            u[r] = 0.f;
#pragma unroll
            for (int j = 0; j < 10; j++) Kf[r][j] = 0.f;
        }
    }

    float vv[10];

    for (int it = 0; it < SINK_IT; it++) {
        // column partials over this thread's 10 rows
        float S[10];
#pragma unroll
        for (int j = 0; j < 10; j++) S[j] = 0.f;
#pragma unroll
        for (int r = 0; r < 10; r++) {
            float ur = u[r];
#pragma unroll
            for (int j = 0; j < 10; j++) S[j] = fmaf(Kf[r][j], ur, S[j]);
        }
        // DPP wave reduction (result in lane 63), lane 63 publishes
#pragma unroll
        for (int j = 0; j < 10; j++) {
            float s = wave_sum63(S[j]);
            if (lane == 63) wred[w][j] = s;
        }
        __syncthreads();
        // 10 threads combine the 8 wave partials, publish v = q / colsum
        if (tid < 10) {
            float s = 0.f;
#pragma unroll
            for (int q = 0; q < 8; q++) s += wred[q][tid];
            ((float*)vbc4)[tid] = 0.1f * frcp(fmaxf(s, 1e-30f));
        }
        __syncthreads();
        {   // broadcast v via 3 x ds_read_b128 (was 10 x b32)
            float4 a = vbc4[0], b = vbc4[1], c = vbc4[2];
            vv[0]=a.x; vv[1]=a.y; vv[2]=a.z; vv[3]=a.w;
            vv[4]=b.x; vv[5]=b.y; vv[6]=b.z; vv[7]=b.w;
            vv[8]=c.x; vv[9]=c.y;
        }
        // row update: u = p / (K v)
#pragma unroll
        for (int r = 0; r < 10; r++) {
            float R = 0.f;
#pragma unroll
            for (int j = 0; j < 10; j++) R = fmaf(Kf[r][j], vv[j], R);
            u[r] = (tid + r * 512 < NND) ? (2e-4f * frcp(fmaxf(R, 1e-30f))) : 0.f;
        }
    }

    // T += step * (u K v - T)
#pragma unroll
    for (int r = 0; r < 10; r++) {
        int i = tid + r * 512;
        if (i < NND) {
            float ur = u[r];
            float2* Tr = (float2*)(Tt + (size_t)i * 10);
#pragma unroll
            for (int h = 0; h < 5; h++) {
                float2 v = Tr[h];
                v.x += step * (ur * Kf[r][2*h]   * vv[2*h]   - v.x);
                v.y += step * (ur * Kf[r][2*h+1] * vv[2*h+1] - v.y);
                Tr[h] = v;
            }
        }
    }
}

// ---------------- final distance + fused linear head ----------------

__global__ __launch_bounds__(256) void k_final(const float* __restrict__ T, const float* __restrict__ Mm,
                                               const float* __restrict__ c1row, const float* __restrict__ c2row,
                                               const float* __restrict__ tpl,
                                               const int* __restrict__ rpS, const int* __restrict__ csrD,
                                               double* __restrict__ dd, int* __restrict__ done,
                                               const float* __restrict__ Wlin,
                                               const float* __restrict__ blin,
                                               float* __restrict__ out) {
    int t = blockIdx.y;
    int tid = threadIdx.x;
    __shared__ float tC2[100];
    if (tid < 100) tC2[tid] = 2.f * tpl[t * 100 + tid];
    __syncthreads();
    int i = blockIdx.x * 256 + tid;
    double msum = 0.0, tsum = 0.0;
    if (i < NND) {
        const float* Tt = T + (size_t)t * NMAT;
        const float* Mt = Mm + (size_t)t * NMAT;
        float L[MT];
#pragma unroll
        for (int j = 0; j < MT; j++) L[j] = 0.f;
        int e0 = rpS[i], e1 = rpS[i + 1];
        for (int e = e0; e < e1; e++) {
            int k = csrD[e];
            const float* Tk = Tt + (size_t)k * MT;
#pragma unroll
            for (int j = 0; j < MT; j++) L[j] += Tk[j];
        }
        float c1 = c1row[i];
#pragma unroll
        for (int j = 0; j < MT; j++) {
            float s = 0.f;
#pragma unroll
            for (int k = 0; k < MT; k++) s += L[k] * tC2[j * 10 + k];
            float ts = c1 + c2row[t * 10 + j] - s;
            float Tv = Tt[(size_t)i * MT + j];
            msum += (double)(Mt[(size_t)i * MT + j] * Tv);
            tsum += (double)(ts * Tv);
        }
    }
    __shared__ double r1[256], r2[256];
    r1[tid] = msum; r2[tid] = tsum; __syncthreads();
    for (int off = 128; off > 0; off >>= 1) {
        if (tid < off) { r1[tid] += r1[tid + off]; r2[tid] += r2[tid + off]; }
        __syncthreads();
    }
    if (tid == 0) {
        atomicAdd(&dd[t * 2], r1[0]);
        atomicAdd(&dd[t * 2 + 1], r2[0]);
        __threadfence();
        int prev = atomicAdd(done, 1);
        if (prev == 20 * NT - 1) {           // last block computes the head
            __threadfence();
            float ds[NT];
#pragma unroll
            for (int k = 0; k < NT; k++) {
                unsigned long long b0 = __hip_atomic_load((unsigned long long*)&dd[2*k],
                                        __ATOMIC_RELAXED, __HIP_MEMORY_SCOPE_AGENT);
                unsigned long long b1 = __hip_atomic_load((unsigned long long*)&dd[2*k+1],
                                        __ATOMIC_RELAXED, __HIP_MEMORY_SCOPE_AGENT);
                ds[k] = 0.5f * (float)(__longlong_as_double(b0) + __longlong_as_double(b1));
            }
#pragma unroll
            for (int c = 0; c < NC; c++) {
                float o = blin[c];
#pragma unroll
                for (int k = 0; k < NT; k++) o = fmaf(ds[k], Wlin[k * NC + c], o);
                out[c] = o;
            }
        }
    }
}

// ---------------- host ----------------

extern "C" void kernel_launch(void* const* d_in, const int* in_sizes, int n_in,
                              void* d_out, int out_size, void* d_ws, size_t ws_size,
                              hipStream_t stream) {
    const float* x    = (const float*)d_in[0];
    const int*   ei   = (const int*)d_in[1];
    const int*   src  = ei;
    const int*   dst  = ei + NE;
    const float* W1   = (const float*)d_in[2];
    const float* b1   = (const float*)d_in[3];
    const float* W2   = (const float*)d_in[4];
    const float* b2   = (const float*)d_in[5];
    const float* tpl  = (const float*)d_in[6];
    const float* tplF = (const float*)d_in[7];
    const float* Wlin = (const float*)d_in[8];
    const float* blin = (const float*)d_in[9];
    float* out = (float*)d_out;

    char* w = (char*)d_ws;
    size_t off = 0;
    auto alloc = [&](size_t b) -> char* {
        off = (off + 255) & ~(size_t)255;
        char* p = w + off; off += b; return p;
    };
    float* bufA = (float*)alloc((size_t)NND * NH * 4);   // aggX / t2 (reused)
    float* bufB = (float*)alloc((size_t)NND * NH * 4);   // h1
    float* bufH = (float*)alloc((size_t)NND * NF * 4);   // h2
    float* Mm   = (float*)alloc((size_t)NT * NMAT * 4);
    float* T    = (float*)alloc((size_t)NT * NMAT * 4);
    float* G    = (float*)alloc((size_t)NT * NMAT * 4);
    // --- zero group (one memset) ---
    int* cntD = (int*)alloc((size_t)NND * 4);
    int* cntS = (int*)alloc((size_t)NND * 4);
    int* cur1 = (int*)alloc((size_t)NND * 4);
    int* cur2 = (int*)alloc((size_t)NND * 4);
    double* dd = (double*)alloc((size_t)NT * 2 * 8);
    int* done = (int*)alloc(4);
    unsigned* scaleArr = (unsigned*)alloc((size_t)CG_ITERS * NT * 4);
    char* zend = w + off;
    // --- rest ---
    unsigned* bitmap = (unsigned*)alloc((size_t)781250 * 4);
    int* rpD  = (int*)alloc((size_t)(NND + 1) * 4);
    int* rpS  = (int*)alloc((size_t)(NND + 1) * 4);
    int* csrS = (int*)alloc((size_t)NE * 4);
    float* csrC = (float*)alloc((size_t)NE * 4);
    int* csrD2 = (int*)alloc((size_t)NE * 4);
    unsigned char* keep = (unsigned char*)alloc((size_t)NE);
    float* dinv  = (float*)alloc((size_t)NND * 4);
    float* c1row = (float*)alloc((size_t)NND * 4);
    float* c2row = (float*)alloc((size_t)100 * 4);

    hipMemsetAsync(cntD, 0, (size_t)(zend - (char*)cntD), stream);
    hipMemsetAsync(bitmap, 0, (size_t)781250 * 4, stream);

    // graph prep (merged passes)
    k_edge1<<<625, 256, 0, stream>>>(src, dst, cntD, bitmap, cntS, keep);
    k_exscan2<<<3, 1024, 0, stream>>>(cntD, rpD, dinv, cntS, rpS, c1row, tpl, c2row);
    k_scatter2<<<625, 256, 0, stream>>>(src, dst, keep, rpD, cur1, csrS, csrC, dinv,
                                        rpS, cur2, csrD2);

    // GCN: layer1 = relu((agg x) @ W1 + b1); layer2 = agg(h1 @ W2) + b2
    k_aggregate<<<625, 256, 0, stream>>>((const float4*)x, nullptr, (float4*)bufA,
                                         rpD, csrS, csrC, dinv);
    k_gemm<<<dim3(NH / 64, (NND + 63) / 64), 256, 0, stream>>>(bufA, W1, bufB, NND, NH, NF, b1, 1);
    k_gemm<<<dim3(NF / 64, (NND + 63) / 64), 256, 0, stream>>>(bufB, W2, bufA, NND, NF, NH, nullptr, 0);
    k_aggregate<<<625, 256, 0, stream>>>((const float4*)bufA, b2, (float4*)bufH,
                                         rpD, csrS, csrC, dinv);

    // FGW prep (M + T init fused)
    k_M<<<NND, 128, 0, stream>>>(bufH, tplF, Mm, T);

    // conditional gradient loop (scale slots pre-zeroed, one per CG iter)
    for (int t = 0; t < CG_ITERS; t++) {
        unsigned* sb = scaleArr + t * NT;
        k_grad<<<dim3(20, NT), 256, 0, stream>>>(T, Mm, c1row, c2row, tpl, rpS, csrD2, G, sb);
        float step = 2.f / (float)(t + 2);
        k_sinkhorn<<<NT, 512, 0, stream>>>(G, sb, T, step);
    }

    // final distances + fused linear head (last block via done-counter)
    k_final<<<dim3(20, NT), 256, 0, stream>>>(T, Mm, c1row, c2row, tpl, rpS, csrD2,
                                              dd, done, Wlin, blin, out);
}